// Round 5
// baseline (2698.074 us; speedup 1.0000x reference)
//
#include <hip/hip_runtime.h>
#include <hip/hip_fp16.h>
#include <stdint.h>

#define TSIZE (1u << 19)
#define NLEV 16
#define NDENSE 5
#define NHASH (NLEV - NDENSE)

// scale_l = 16 * (256^(l/15)) - 1
__device__ constexpr float SC[NLEV] = {
    15.0f,          22.1563078f,   32.5134119f,   47.5029301f,
    69.1967987f,    100.5936673f,  146.0333894f,  211.7969328f,
    306.9744096f,   444.7218880f,  644.0795776f,  932.6038304f,
    1350.1761008f,  1954.5156576f, 2829.1576190f, 4095.0f};
__device__ constexpr uint32_t RES[NDENSE] = {16u, 24u, 34u, 49u, 71u};

static __device__ __forceinline__ uint32_t umin32(uint32_t a, uint32_t b) {
    return a < b ? a : b;
}

static __device__ __forceinline__ void hash_idx(int l, float ux, float uy, float uz,
                                                uint32_t* idxs) {
    const float s = SC[l];
    uint32_t x0 = (uint32_t)floorf(fmaf(ux, s, 0.5f));
    uint32_t y0 = (uint32_t)floorf(fmaf(uy, s, 0.5f));
    uint32_t z0 = (uint32_t)floorf(fmaf(uz, s, 0.5f));
    uint32_t hy0 = y0 * 2654435761u;
    uint32_t hz0 = z0 * 805459861u;
    uint32_t hx[2] = {x0, x0 + 1u};
    uint32_t hy[2] = {hy0, hy0 + 2654435761u};
    uint32_t hz[2] = {hz0, hz0 + 805459861u};
#pragma unroll
    for (int c = 0; c < 8; ++c)
        idxs[c] = (hx[c & 1] ^ hy[(c >> 1) & 1] ^ hz[c >> 2]) & (TSIZE - 1u);
}

static __device__ __forceinline__ void dense_idx(int l, float ux, float uy, float uz,
                                                 uint32_t* idxs) {
    const float s = SC[l];
    const uint32_t R = RES[l];
    uint32_t x0 = (uint32_t)floorf(fmaf(ux, s, 0.5f));
    uint32_t y0 = (uint32_t)floorf(fmaf(uy, s, 0.5f));
    uint32_t z0 = (uint32_t)floorf(fmaf(uz, s, 0.5f));
    uint32_t xs[2] = {umin32(x0, R - 1u), umin32(x0 + 1u, R - 1u)};
    uint32_t ys[2] = {umin32(y0, R - 1u), umin32(y0 + 1u, R - 1u)};
    uint32_t zs[2] = {umin32(z0, R - 1u), umin32(z0 + 1u, R - 1u)};
#pragma unroll
    for (int c = 0; c < 8; ++c)
        idxs[c] = xs[c & 1] + ys[(c >> 1) & 1] * R + zs[c >> 2] * R * R;
}

// trilinear weights for level l
static __device__ __forceinline__ void level_w(int l, float ux, float uy, float uz,
                                               float* wx, float* wy, float* wz) {
    const float s = SC[l];
    float px = fmaf(ux, s, 0.5f);
    float py = fmaf(uy, s, 0.5f);
    float pz = fmaf(uz, s, 0.5f);
    float rx = px - floorf(px), ry = py - floorf(py), rz = pz - floorf(pz);
    wx[0] = 1.f - rx; wx[1] = rx;
    wy[0] = 1.f - ry; wy[1] = ry;
    wz[0] = 1.f - rz; wz[1] = rz;
}

__global__ __launch_bounds__(256) void convert_grid(const float2* __restrict__ g,
                                                    __half2* __restrict__ o, int n) {
    int i = blockIdx.x * 256 + threadIdx.x;
    if (i < n) {
        float2 v = g[i];
        o[i] = __floats2half2_rn(v.x, v.y);
    }
}

__global__ __launch_bounds__(256, 3) void mlp_tex3d_h(
    const float* __restrict__ texc,
    const __half2* __restrict__ gws,
    const float* __restrict__ W0,
    const float* __restrict__ W1,
    const float* __restrict__ W2,
    const float* __restrict__ aabb,
    const float* __restrict__ mm,
    float* __restrict__ out,
    int N)
{
    int i = blockIdx.x * 256 + threadIdx.x;
    if (i >= N) return;

    float t0 = texc[3 * i + 0], t1 = texc[3 * i + 1], t2 = texc[3 * i + 2];
    float ux = fminf(fmaxf((t0 - aabb[0]) / (aabb[3] - aabb[0]), 0.f), 1.f);
    float uy = fminf(fmaxf((t1 - aabb[1]) / (aabb[4] - aabb[1]), 0.f), 1.f);
    float uz = fminf(fmaxf((t2 - aabb[2]) / (aabb[5] - aabb[2]), 0.f), 1.f);

    // ---- Phase A: issue ALL hashed-level gathers (long latency, cache-cold) ----
    __half2 gb[NHASH][8];                     // 88 VGPRs of in-flight data
#pragma unroll
    for (int l = NDENSE; l < NLEV; ++l) {
        uint32_t idxs[8];
        hash_idx(l, ux, uy, uz, idxs);
        const __half2* __restrict__ gl = gws + (size_t)l * TSIZE;
#pragma unroll
        for (int c = 0; c < 8; ++c) gb[l - NDENSE][c] = gl[idxs[c]];
    }
    // pin: nothing above may sink below, nothing below may hoist above
    __builtin_amdgcn_sched_barrier(0);

    // ---- Phase B: dense levels inline (cache-hot) + layer-0 accumulation ----
    float h[32];
#pragma unroll
    for (int j = 0; j < 32; ++j) h[j] = 0.f;

#pragma unroll
    for (int l = 0; l < NDENSE; ++l) {
        uint32_t idxs[8];
        dense_idx(l, ux, uy, uz, idxs);
        const __half2* __restrict__ gl = gws + (size_t)l * TSIZE;
        float wx[2], wy[2], wz[2];
        level_w(l, ux, uy, uz, wx, wy, wz);
        float f0 = 0.f, f1 = 0.f;
#pragma unroll
        for (int c = 0; c < 8; ++c) {
            float2 g = __half22float2(gl[idxs[c]]);
            float w = wx[c & 1] * wy[(c >> 1) & 1] * wz[c >> 2];
            f0 = fmaf(w, g.x, f0);
            f1 = fmaf(w, g.y, f1);
        }
#pragma unroll
        for (int j = 0; j < 32; ++j) {
            h[j] = fmaf(f0, W0[j * 32 + 2 * l], h[j]);
            h[j] = fmaf(f1, W0[j * 32 + 2 * l + 1], h[j]);
        }
    }

    // ---- Phase C: consume hashed levels in issue order (incremental vmcnt) ----
#pragma unroll
    for (int l = NDENSE; l < NLEV; ++l) {
        float wx[2], wy[2], wz[2];
        level_w(l, ux, uy, uz, wx, wy, wz);
        float f0 = 0.f, f1 = 0.f;
#pragma unroll
        for (int c = 0; c < 8; ++c) {
            float2 g = __half22float2(gb[l - NDENSE][c]);
            float w = wx[c & 1] * wy[(c >> 1) & 1] * wz[c >> 2];
            f0 = fmaf(w, g.x, f0);
            f1 = fmaf(w, g.y, f1);
        }
#pragma unroll
        for (int j = 0; j < 32; ++j) {
            h[j] = fmaf(f0, W0[j * 32 + 2 * l], h[j]);
            h[j] = fmaf(f1, W0[j * 32 + 2 * l + 1], h[j]);
        }
    }

    // ---- MLP layers 1,2 ----
    float h2[32];
#pragma unroll
    for (int j = 0; j < 32; ++j) h[j] = fmaxf(h[j], 0.f);
#pragma unroll
    for (int j = 0; j < 32; ++j) {
        float a = 0.f;
#pragma unroll
        for (int k = 0; k < 32; ++k) a = fmaf(h[k], W1[j * 32 + k], a);
        h2[j] = fmaxf(a, 0.f);
    }
#pragma unroll
    for (int j = 0; j < 9; ++j) {
        float a = 0.f;
#pragma unroll
        for (int k = 0; k < 32; ++k) a = fmaf(h2[k], W2[j * 32 + k], a);
        float sg = 1.0f / (1.0f + __expf(-a));
        out[(size_t)i * 9 + j] = fmaf(sg, mm[9 + j] - mm[j], mm[j]);
    }
}

// fallback (f32 gathers, no ws) — same as R1
__global__ __launch_bounds__(256) void mlp_tex3d_f(
    const float* __restrict__ texc, const float2* __restrict__ grid,
    const float* __restrict__ W0, const float* __restrict__ W1,
    const float* __restrict__ W2, const float* __restrict__ aabb,
    const float* __restrict__ mm, float* __restrict__ out, int N)
{
    int i = blockIdx.x * 256 + threadIdx.x;
    if (i >= N) return;
    float t0 = texc[3 * i + 0], t1 = texc[3 * i + 1], t2 = texc[3 * i + 2];
    float ux = fminf(fmaxf((t0 - aabb[0]) / (aabb[3] - aabb[0]), 0.f), 1.f);
    float uy = fminf(fmaxf((t1 - aabb[1]) / (aabb[4] - aabb[1]), 0.f), 1.f);
    float uz = fminf(fmaxf((t2 - aabb[2]) / (aabb[5] - aabb[2]), 0.f), 1.f);
    float enc[32];
#pragma unroll
    for (int l = 0; l < NLEV; ++l) {
        uint32_t idxs[8];
        if (l < NDENSE) dense_idx(l, ux, uy, uz, idxs);
        else            hash_idx(l, ux, uy, uz, idxs);
        float wx[2], wy[2], wz[2];
        level_w(l, ux, uy, uz, wx, wy, wz);
        const float2* __restrict__ gl = grid + (size_t)l * TSIZE;
        float f0 = 0.f, f1 = 0.f;
#pragma unroll
        for (int c = 0; c < 8; ++c) {
            float2 g = gl[idxs[c]];
            float w = wx[c & 1] * wy[(c >> 1) & 1] * wz[c >> 2];
            f0 = fmaf(w, g.x, f0);
            f1 = fmaf(w, g.y, f1);
        }
        enc[2 * l + 0] = f0;
        enc[2 * l + 1] = f1;
    }
    float h[32];
#pragma unroll
    for (int j = 0; j < 32; ++j) {
        float a = 0.f;
#pragma unroll
        for (int k = 0; k < 32; ++k) a = fmaf(enc[k], W0[j * 32 + k], a);
        h[j] = fmaxf(a, 0.f);
    }
#pragma unroll
    for (int j = 0; j < 32; ++j) {
        float a = 0.f;
#pragma unroll
        for (int k = 0; k < 32; ++k) a = fmaf(h[k], W1[j * 32 + k], a);
        enc[j] = fmaxf(a, 0.f);
    }
#pragma unroll
    for (int j = 0; j < 9; ++j) {
        float a = 0.f;
#pragma unroll
        for (int k = 0; k < 32; ++k) a = fmaf(enc[k], W2[j * 32 + k], a);
        float sg = 1.0f / (1.0f + __expf(-a));
        out[(size_t)i * 9 + j] = fmaf(sg, mm[9 + j] - mm[j], mm[j]);
    }
}

extern "C" void kernel_launch(void* const* d_in, const int* in_sizes, int n_in,
                              void* d_out, int out_size, void* d_ws, size_t ws_size,
                              hipStream_t stream) {
    const float*  texc = (const float*)d_in[0];
    const float2* grid = (const float2*)d_in[1];
    const float*  W0   = (const float*)d_in[2];
    const float*  W1   = (const float*)d_in[3];
    const float*  W2   = (const float*)d_in[4];
    const float*  aabb = (const float*)d_in[5];
    const float*  mm   = (const float*)d_in[6];
    float* out = (float*)d_out;

    int N = in_sizes[0] / 3;
    int blocks = (N + 255) / 256;
    const int ngrid = NLEV * TSIZE;
    const size_t need = (size_t)ngrid * sizeof(__half2);

    if (ws_size >= need) {
        __half2* gws = (__half2*)d_ws;
        convert_grid<<<(ngrid + 255) / 256, 256, 0, stream>>>(grid, gws, ngrid);
        mlp_tex3d_h<<<blocks, 256, 0, stream>>>(texc, gws, W0, W1, W2, aabb, mm, out, N);
    } else {
        mlp_tex3d_f<<<blocks, 256, 0, stream>>>(texc, grid, W0, W1, W2, aabb, mm, out, N);
    }
}

// Round 6
// 1961.279 us; speedup vs baseline: 1.3757x; 1.3757x over previous
//
#include <hip/hip_runtime.h>
#include <hip/hip_fp16.h>
#include <stdint.h>

#define TSIZE (1u << 19)
#define NLEV 16
#define NDENSE 5

// scale_l = 16 * (256^(l/15)) - 1
__device__ constexpr float SC[NLEV] = {
    15.0f,          22.1563078f,   32.5134119f,   47.5029301f,
    69.1967987f,    100.5936673f,  146.0333894f,  211.7969328f,
    306.9744096f,   444.7218880f,  644.0795776f,  932.6038304f,
    1350.1761008f,  1954.5156576f, 2829.1576190f, 4095.0f};
__device__ constexpr uint32_t RES[NDENSE] = {16u, 24u, 34u, 49u, 71u};

static __device__ __forceinline__ uint32_t umin32(uint32_t a, uint32_t b) {
    return a < b ? a : b;
}

__global__ __launch_bounds__(256) void convert_grid(const float2* __restrict__ g,
                                                    __half2* __restrict__ o, int n) {
    int i = blockIdx.x * 256 + threadIdx.x;
    if (i < n) {
        float2 v = g[i];
        o[i] = __floats2half2_rn(v.x, v.y);
    }
}

// One thread = one (point, level). blockIdx.y = level. Massive TLP for the
// divergent gathers; dispatch is x-major so levels run ~sequentially -> the
// active 2MB table stays L2-resident.
__global__ __launch_bounds__(256) void k_gather(
    const float* __restrict__ texc,
    const __half2* __restrict__ gws,
    const float* __restrict__ aabb,
    __half2* __restrict__ feat,     // [NLEV][N]
    int N)
{
    int i = blockIdx.x * 256 + threadIdx.x;
    if (i >= N) return;
    const int l = blockIdx.y;

    float t0 = texc[3 * i + 0], t1 = texc[3 * i + 1], t2 = texc[3 * i + 2];
    float ux = fminf(fmaxf((t0 - aabb[0]) / (aabb[3] - aabb[0]), 0.f), 1.f);
    float uy = fminf(fmaxf((t1 - aabb[1]) / (aabb[4] - aabb[1]), 0.f), 1.f);
    float uz = fminf(fmaxf((t2 - aabb[2]) / (aabb[5] - aabb[2]), 0.f), 1.f);

    const float s = SC[l];                    // uniform runtime index -> s_load
    float px = fmaf(ux, s, 0.5f);
    float py = fmaf(uy, s, 0.5f);
    float pz = fmaf(uz, s, 0.5f);
    float fx = floorf(px), fy = floorf(py), fz = floorf(pz);
    float rx = px - fx, ry = py - fy, rz = pz - fz;
    uint32_t x0 = (uint32_t)fx, y0 = (uint32_t)fy, z0 = (uint32_t)fz;

    uint32_t idxs[8];
    if (l < NDENSE) {                         // block-uniform branch
        const uint32_t R = RES[l];
        uint32_t xs[2] = {umin32(x0, R - 1u), umin32(x0 + 1u, R - 1u)};
        uint32_t ys[2] = {umin32(y0, R - 1u), umin32(y0 + 1u, R - 1u)};
        uint32_t zs[2] = {umin32(z0, R - 1u), umin32(z0 + 1u, R - 1u)};
#pragma unroll
        for (int c = 0; c < 8; ++c)
            idxs[c] = xs[c & 1] + ys[(c >> 1) & 1] * R + zs[c >> 2] * R * R;
    } else {
        uint32_t hy0 = y0 * 2654435761u;
        uint32_t hz0 = z0 * 805459861u;
        uint32_t hx[2] = {x0, x0 + 1u};
        uint32_t hy[2] = {hy0, hy0 + 2654435761u};
        uint32_t hz[2] = {hz0, hz0 + 805459861u};
#pragma unroll
        for (int c = 0; c < 8; ++c)
            idxs[c] = (hx[c & 1] ^ hy[(c >> 1) & 1] ^ hz[c >> 2]) & (TSIZE - 1u);
    }

    const __half2* __restrict__ gl = gws + (size_t)l * TSIZE;
    float wx[2] = {1.f - rx, rx};
    float wy[2] = {1.f - ry, ry};
    float wz[2] = {1.f - rz, rz};
    float f0 = 0.f, f1 = 0.f;
#pragma unroll
    for (int c = 0; c < 8; ++c) {
        float2 g = __half22float2(gl[idxs[c]]);
        float w = wx[c & 1] * wy[(c >> 1) & 1] * wz[c >> 2];
        f0 = fmaf(w, g.x, f0);
        f1 = fmaf(w, g.y, f1);
    }
    feat[(size_t)l * N + i] = __floats2half2_rn(f0, f1);   // coalesced
}

// One thread = one point. 16 coalesced feature loads + MLP. Weights via
// uniform s_load through K$.
__global__ __launch_bounds__(256) void k_mlp(
    const __half2* __restrict__ feat,   // [NLEV][N]
    const float* __restrict__ W0,
    const float* __restrict__ W1,
    const float* __restrict__ W2,
    const float* __restrict__ mm,
    float* __restrict__ out,
    int N)
{
    int i = blockIdx.x * 256 + threadIdx.x;
    if (i >= N) return;

    float h[32];
#pragma unroll
    for (int j = 0; j < 32; ++j) h[j] = 0.f;

#pragma unroll
    for (int l = 0; l < NLEV; ++l) {
        float2 f = __half22float2(feat[(size_t)l * N + i]);
#pragma unroll
        for (int j = 0; j < 32; ++j) {
            h[j] = fmaf(f.x, W0[j * 32 + 2 * l], h[j]);
            h[j] = fmaf(f.y, W0[j * 32 + 2 * l + 1], h[j]);
        }
    }

    float h2[32];
#pragma unroll
    for (int j = 0; j < 32; ++j) h[j] = fmaxf(h[j], 0.f);
#pragma unroll
    for (int j = 0; j < 32; ++j) {
        float a = 0.f;
#pragma unroll
        for (int k = 0; k < 32; ++k) a = fmaf(h[k], W1[j * 32 + k], a);
        h2[j] = fmaxf(a, 0.f);
    }
#pragma unroll
    for (int j = 0; j < 9; ++j) {
        float a = 0.f;
#pragma unroll
        for (int k = 0; k < 32; ++k) a = fmaf(h2[k], W2[j * 32 + k], a);
        float sg = 1.0f / (1.0f + __expf(-a));
        out[(size_t)i * 9 + j] = fmaf(sg, mm[9 + j] - mm[j], mm[j]);
    }
}

// ---------------- fallbacks ----------------
static __device__ __forceinline__ void hash_idx_c(int l, float ux, float uy, float uz,
                                                  uint32_t* idxs) {
    const float s = SC[l];
    uint32_t x0 = (uint32_t)floorf(fmaf(ux, s, 0.5f));
    uint32_t y0 = (uint32_t)floorf(fmaf(uy, s, 0.5f));
    uint32_t z0 = (uint32_t)floorf(fmaf(uz, s, 0.5f));
    uint32_t hy0 = y0 * 2654435761u;
    uint32_t hz0 = z0 * 805459861u;
    uint32_t hx[2] = {x0, x0 + 1u};
    uint32_t hy[2] = {hy0, hy0 + 2654435761u};
    uint32_t hz[2] = {hz0, hz0 + 805459861u};
#pragma unroll
    for (int c = 0; c < 8; ++c)
        idxs[c] = (hx[c & 1] ^ hy[(c >> 1) & 1] ^ hz[c >> 2]) & (TSIZE - 1u);
}

static __device__ __forceinline__ void dense_idx_c(int l, float ux, float uy, float uz,
                                                   uint32_t* idxs) {
    const float s = SC[l];
    const uint32_t R = RES[l];
    uint32_t x0 = (uint32_t)floorf(fmaf(ux, s, 0.5f));
    uint32_t y0 = (uint32_t)floorf(fmaf(uy, s, 0.5f));
    uint32_t z0 = (uint32_t)floorf(fmaf(uz, s, 0.5f));
    uint32_t xs[2] = {umin32(x0, R - 1u), umin32(x0 + 1u, R - 1u)};
    uint32_t ys[2] = {umin32(y0, R - 1u), umin32(y0 + 1u, R - 1u)};
    uint32_t zs[2] = {umin32(z0, R - 1u), umin32(z0 + 1u, R - 1u)};
#pragma unroll
    for (int c = 0; c < 8; ++c)
        idxs[c] = xs[c & 1] + ys[(c >> 1) & 1] * R + zs[c >> 2] * R * R;
}

static __device__ __forceinline__ void level_w_c(int l, float ux, float uy, float uz,
                                                 float* wx, float* wy, float* wz) {
    const float s = SC[l];
    float px = fmaf(ux, s, 0.5f);
    float py = fmaf(uy, s, 0.5f);
    float pz = fmaf(uz, s, 0.5f);
    float rx = px - floorf(px), ry = py - floorf(py), rz = pz - floorf(pz);
    wx[0] = 1.f - rx; wx[1] = rx;
    wy[0] = 1.f - ry; wy[1] = ry;
    wz[0] = 1.f - rz; wz[1] = rz;
}

// R2-style fused fp16 kernel (measured 2222us) — used if ws too small for feat
__global__ __launch_bounds__(256) void mlp_tex3d_h(
    const float* __restrict__ texc, const __half2* __restrict__ gws,
    const float* __restrict__ W0, const float* __restrict__ W1,
    const float* __restrict__ W2, const float* __restrict__ aabb,
    const float* __restrict__ mm, float* __restrict__ out, int N)
{
    int i = blockIdx.x * 256 + threadIdx.x;
    if (i >= N) return;
    float t0 = texc[3 * i + 0], t1 = texc[3 * i + 1], t2 = texc[3 * i + 2];
    float ux = fminf(fmaxf((t0 - aabb[0]) / (aabb[3] - aabb[0]), 0.f), 1.f);
    float uy = fminf(fmaxf((t1 - aabb[1]) / (aabb[4] - aabb[1]), 0.f), 1.f);
    float uz = fminf(fmaxf((t2 - aabb[2]) / (aabb[5] - aabb[2]), 0.f), 1.f);
    float enc[32];
#pragma unroll
    for (int l = 0; l < NLEV; ++l) {
        uint32_t idxs[8];
        if (l < NDENSE) dense_idx_c(l, ux, uy, uz, idxs);
        else            hash_idx_c(l, ux, uy, uz, idxs);
        float wx[2], wy[2], wz[2];
        level_w_c(l, ux, uy, uz, wx, wy, wz);
        const __half2* __restrict__ gl = gws + (size_t)l * TSIZE;
        float f0 = 0.f, f1 = 0.f;
#pragma unroll
        for (int c = 0; c < 8; ++c) {
            float2 g = __half22float2(gl[idxs[c]]);
            float w = wx[c & 1] * wy[(c >> 1) & 1] * wz[c >> 2];
            f0 = fmaf(w, g.x, f0);
            f1 = fmaf(w, g.y, f1);
        }
        enc[2 * l + 0] = f0;
        enc[2 * l + 1] = f1;
    }
    float h[32];
#pragma unroll
    for (int j = 0; j < 32; ++j) {
        float a = 0.f;
#pragma unroll
        for (int k = 0; k < 32; ++k) a = fmaf(enc[k], W0[j * 32 + k], a);
        h[j] = fmaxf(a, 0.f);
    }
#pragma unroll
    for (int j = 0; j < 32; ++j) {
        float a = 0.f;
#pragma unroll
        for (int k = 0; k < 32; ++k) a = fmaf(h[k], W1[j * 32 + k], a);
        enc[j] = fmaxf(a, 0.f);
    }
#pragma unroll
    for (int j = 0; j < 9; ++j) {
        float a = 0.f;
#pragma unroll
        for (int k = 0; k < 32; ++k) a = fmaf(enc[k], W2[j * 32 + k], a);
        float sg = 1.0f / (1.0f + __expf(-a));
        out[(size_t)i * 9 + j] = fmaf(sg, mm[9 + j] - mm[j], mm[j]);
    }
}

// pure-f32 fallback (no ws at all)
__global__ __launch_bounds__(256) void mlp_tex3d_f(
    const float* __restrict__ texc, const float2* __restrict__ grid,
    const float* __restrict__ W0, const float* __restrict__ W1,
    const float* __restrict__ W2, const float* __restrict__ aabb,
    const float* __restrict__ mm, float* __restrict__ out, int N)
{
    int i = blockIdx.x * 256 + threadIdx.x;
    if (i >= N) return;
    float t0 = texc[3 * i + 0], t1 = texc[3 * i + 1], t2 = texc[3 * i + 2];
    float ux = fminf(fmaxf((t0 - aabb[0]) / (aabb[3] - aabb[0]), 0.f), 1.f);
    float uy = fminf(fmaxf((t1 - aabb[1]) / (aabb[4] - aabb[1]), 0.f), 1.f);
    float uz = fminf(fmaxf((t2 - aabb[2]) / (aabb[5] - aabb[2]), 0.f), 1.f);
    float enc[32];
#pragma unroll
    for (int l = 0; l < NLEV; ++l) {
        uint32_t idxs[8];
        if (l < NDENSE) dense_idx_c(l, ux, uy, uz, idxs);
        else            hash_idx_c(l, ux, uy, uz, idxs);
        float wx[2], wy[2], wz[2];
        level_w_c(l, ux, uy, uz, wx, wy, wz);
        const float2* __restrict__ gl = grid + (size_t)l * TSIZE;
        float f0 = 0.f, f1 = 0.f;
#pragma unroll
        for (int c = 0; c < 8; ++c) {
            float2 g = gl[idxs[c]];
            float w = wx[c & 1] * wy[(c >> 1) & 1] * wz[c >> 2];
            f0 = fmaf(w, g.x, f0);
            f1 = fmaf(w, g.y, f1);
        }
        enc[2 * l + 0] = f0;
        enc[2 * l + 1] = f1;
    }
    float h[32];
#pragma unroll
    for (int j = 0; j < 32; ++j) {
        float a = 0.f;
#pragma unroll
        for (int k = 0; k < 32; ++k) a = fmaf(enc[k], W0[j * 32 + k], a);
        h[j] = fmaxf(a, 0.f);
    }
#pragma unroll
    for (int j = 0; j < 32; ++j) {
        float a = 0.f;
#pragma unroll
        for (int k = 0; k < 32; ++k) a = fmaf(h[k], W1[j * 32 + k], a);
        enc[j] = fmaxf(a, 0.f);
    }
#pragma unroll
    for (int j = 0; j < 9; ++j) {
        float a = 0.f;
#pragma unroll
        for (int k = 0; k < 32; ++k) a = fmaf(enc[k], W2[j * 32 + k], a);
        float sg = 1.0f / (1.0f + __expf(-a));
        out[(size_t)i * 9 + j] = fmaf(sg, mm[9 + j] - mm[j], mm[j]);
    }
}

extern "C" void kernel_launch(void* const* d_in, const int* in_sizes, int n_in,
                              void* d_out, int out_size, void* d_ws, size_t ws_size,
                              hipStream_t stream) {
    const float*  texc = (const float*)d_in[0];
    const float2* grid = (const float2*)d_in[1];
    const float*  W0   = (const float*)d_in[2];
    const float*  W1   = (const float*)d_in[3];
    const float*  W2   = (const float*)d_in[4];
    const float*  aabb = (const float*)d_in[5];
    const float*  mm   = (const float*)d_in[6];
    float* out = (float*)d_out;

    int N = in_sizes[0] / 3;
    int blocks = (N + 255) / 256;
    const int ngrid = NLEV * TSIZE;
    const size_t need_grid = (size_t)ngrid * sizeof(__half2);          // 33.5 MB
    const size_t need_feat = (size_t)NLEV * (size_t)N * sizeof(__half2); // 268 MB

    if (ws_size >= need_grid + need_feat) {
        __half2* gws  = (__half2*)d_ws;
        __half2* feat = (__half2*)((char*)d_ws + need_grid);
        convert_grid<<<(ngrid + 255) / 256, 256, 0, stream>>>(grid, gws, ngrid);
        dim3 gg(blocks, NLEV);
        k_gather<<<gg, 256, 0, stream>>>(texc, gws, aabb, feat, N);
        k_mlp<<<blocks, 256, 0, stream>>>(feat, W0, W1, W2, mm, out, N);
    } else if (ws_size >= need_grid) {
        __half2* gws = (__half2*)d_ws;
        convert_grid<<<(ngrid + 255) / 256, 256, 0, stream>>>(grid, gws, ngrid);
        mlp_tex3d_h<<<blocks, 256, 0, stream>>>(texc, gws, W0, W1, W2, aabb, mm, out, N);
    } else {
        mlp_tex3d_f<<<blocks, 256, 0, stream>>>(texc, grid, W0, W1, W2, aabb, mm, out, N);
    }
}